// Round 1
// baseline (11207.923 us; speedup 1.0000x reference)
//
#include <hip/hip_runtime.h>
#include <hip/hip_bf16.h>
#include <cstdint>

#define S 2048
#define NH 32
#define HD 64
#define NJ 34              // 32 q heads + k + v
#define FUSED_N (NJ * HD)  // 2176
#define HDIM (NH * HD)     // 2048
#define HEAVY_K 128
#define RECENT_W 128
#define START_T 256

// ---------------------------------------------------------------------------
// GEMM: C[M x N] = A[M x K] * B[N x K]^T   (fp32, all dims multiples of tile)
// tile 128(M) x 64(N), K-step 16, 256 threads, 8x4 micro-tile
// ---------------------------------------------------------------------------
__global__ __launch_bounds__(256) void gemm_nt_kernel(const float* __restrict__ A,
                                                      const float* __restrict__ B,
                                                      float* __restrict__ C,
                                                      int K, int N)
{
    __shared__ float As[16][132];
    __shared__ float Bs[16][68];
    const int bm = blockIdx.y * 128;
    const int bn = blockIdx.x * 64;
    const int tid = threadIdx.x;
    const int tm = (tid >> 4) * 8;
    const int tn = (tid & 15) * 4;
    const int lr = tid >> 2;          // 0..63
    const int lk = (tid & 3) * 4;     // 0,4,8,12
    float acc[8][4] = {};
    const float* Ap0 = A + (size_t)(bm + lr) * K + lk;
    const float* Ap1 = Ap0 + (size_t)64 * K;
    const float* Bp  = B + (size_t)(bn + lr) * K + lk;
    for (int k0 = 0; k0 < K; k0 += 16) {
        float4 a0 = *(const float4*)(Ap0 + k0);
        float4 a1 = *(const float4*)(Ap1 + k0);
        float4 b0 = *(const float4*)(Bp + k0);
        As[lk + 0][lr] = a0.x; As[lk + 1][lr] = a0.y; As[lk + 2][lr] = a0.z; As[lk + 3][lr] = a0.w;
        As[lk + 0][lr + 64] = a1.x; As[lk + 1][lr + 64] = a1.y; As[lk + 2][lr + 64] = a1.z; As[lk + 3][lr + 64] = a1.w;
        Bs[lk + 0][lr] = b0.x; Bs[lk + 1][lr] = b0.y; Bs[lk + 2][lr] = b0.z; Bs[lk + 3][lr] = b0.w;
        __syncthreads();
#pragma unroll
        for (int kk = 0; kk < 16; ++kk) {
            float4 av0 = *(const float4*)&As[kk][tm];
            float4 av1 = *(const float4*)&As[kk][tm + 4];
            float4 bv  = *(const float4*)&Bs[kk][tn];
            float a8[8] = {av0.x, av0.y, av0.z, av0.w, av1.x, av1.y, av1.z, av1.w};
            float b4[4] = {bv.x, bv.y, bv.z, bv.w};
#pragma unroll
            for (int i = 0; i < 8; ++i)
#pragma unroll
                for (int j = 0; j < 4; ++j)
                    acc[i][j] += a8[i] * b4[j];
        }
        __syncthreads();
    }
#pragma unroll
    for (int i = 0; i < 8; ++i) {
        float4 r = make_float4(acc[i][0], acc[i][1], acc[i][2], acc[i][3]);
        *(float4*)(C + (size_t)(bm + tm + i) * N + (bn + tn)) = r;
    }
}

// ---------------------------------------------------------------------------
// RoPE + split fused -> q [S][2048], k [S][64], v [S][64]
// ---------------------------------------------------------------------------
__global__ __launch_bounds__(256) void rope_split_kernel(const float* __restrict__ fused,
                                                         float* __restrict__ q,
                                                         float* __restrict__ k,
                                                         float* __restrict__ v)
{
    int idx = blockIdx.x * 256 + threadIdx.x;
    const int total = S * NJ * HD;
    if (idx >= total) return;
    int t = idx / FUSED_N;
    int rem = idx - t * FUSED_N;
    int j = rem >> 6;
    int d = rem & 63;
    float x = fused[idx];
    if (j == 33) { v[t * HD + d] = x; return; }
    int i = d & 31;
    // inv = 10000^(-i/32), angle computed in double for accuracy
    double inv = exp2(-(double)i * (13.287712379549449 / 32.0));
    double ang = (double)t * inv;
    float c  = (float)cos(ang);
    float sn = (float)sin(ang);
    float xo = fused[idx - d + ((d < 32) ? (d + 32) : (d - 32))];
    float rot = (d < 32) ? -xo : xo;
    float outv = x * c + rot * sn;
    if (j == 32) k[t * HD + d] = outv;
    else         q[(size_t)t * HDIM + j * HD + d] = outv;
}

// ---------------------------------------------------------------------------
// P[t][c] = sum_h softmax_c(q_h[t]·k[c]/8)   (full non-causal row softmax)
// one block per row t; two passes (Z, then P); k cached in regs (2 cols/thr)
// ---------------------------------------------------------------------------
__global__ __launch_bounds__(256) void p_kernel(const float* __restrict__ q,
                                                const float* __restrict__ k,
                                                float* __restrict__ P)
{
    const int t = blockIdx.x;
    const int tid = threadIdx.x;
    __shared__ float qs[HDIM];
    __shared__ float zw[NH][4];
    __shared__ float zf[NH];
    for (int i2 = tid; i2 < HDIM; i2 += 256) qs[i2] = q[(size_t)t * HDIM + i2];
    float zacc[NH];
#pragma unroll
    for (int h = 0; h < NH; ++h) zacc[h] = 0.f;
    __syncthreads();
    // ---- pass A: Z per head ----
    for (int ch = 0; ch < 4; ++ch) {
        const int c0 = ch * 512 + tid * 2;
        float4 ka[16], kb[16];
        const float4* kp = (const float4*)(k + (size_t)c0 * HD);
#pragma unroll
        for (int dq = 0; dq < 16; ++dq) { ka[dq] = kp[dq]; kb[dq] = kp[dq + 16]; }
#pragma unroll
        for (int h = 0; h < NH; ++h) {
            const float4* qp = (const float4*)(qs + h * HD);
            float s0 = 0.f, s1 = 0.f;
#pragma unroll
            for (int dq = 0; dq < 16; ++dq) {
                float4 q4 = qp[dq];
                s0 += q4.x * ka[dq].x + q4.y * ka[dq].y + q4.z * ka[dq].z + q4.w * ka[dq].w;
                s1 += q4.x * kb[dq].x + q4.y * kb[dq].y + q4.z * kb[dq].z + q4.w * kb[dq].w;
            }
            zacc[h] += __expf(s0 * 0.125f) + __expf(s1 * 0.125f);
        }
    }
#pragma unroll
    for (int h = 0; h < NH; ++h) {
        float z = zacc[h];
        for (int off = 32; off > 0; off >>= 1) z += __shfl_down(z, off);
        zacc[h] = z;
    }
    {
        const int wid = tid >> 6, lane = tid & 63;
        if (lane == 0) {
#pragma unroll
            for (int h = 0; h < NH; ++h) zw[h][wid] = zacc[h];
        }
    }
    __syncthreads();
    if (tid < NH) zf[tid] = 1.0f / (zw[tid][0] + zw[tid][1] + zw[tid][2] + zw[tid][3]);
    __syncthreads();
    // ---- pass B: P row ----
    for (int ch = 0; ch < 4; ++ch) {
        const int c0 = ch * 512 + tid * 2;
        float4 ka[16], kb[16];
        const float4* kp = (const float4*)(k + (size_t)c0 * HD);
#pragma unroll
        for (int dq = 0; dq < 16; ++dq) { ka[dq] = kp[dq]; kb[dq] = kp[dq + 16]; }
        float p0 = 0.f, p1 = 0.f;
#pragma unroll
        for (int h = 0; h < NH; ++h) {
            const float4* qp = (const float4*)(qs + h * HD);
            float s0 = 0.f, s1 = 0.f;
#pragma unroll
            for (int dq = 0; dq < 16; ++dq) {
                float4 q4 = qp[dq];
                s0 += q4.x * ka[dq].x + q4.y * ka[dq].y + q4.z * ka[dq].z + q4.w * ka[dq].w;
                s1 += q4.x * kb[dq].x + q4.y * kb[dq].y + q4.z * kb[dq].z + q4.w * kb[dq].w;
            }
            float zi = zf[h];
            p0 += __expf(s0 * 0.125f) * zi;
            p1 += __expf(s1 * 0.125f) * zi;
        }
        P[(size_t)t * S + c0]     = p0;
        P[(size_t)t * S + c0 + 1] = p1;
    }
}

// ---------------------------------------------------------------------------
// Sequential heavy-hitter scan. Single block of 64 threads (1 wave).
// Candidates at step t = previous 128 heavy cols + col (t-129): evict min
// (ties -> evict larger column, matching lax.top_k ascending-index tie-break).
// ---------------------------------------------------------------------------
__global__ void scan_kernel(const float* __restrict__ P, unsigned short* __restrict__ heavy)
{
    __shared__ float acc[S];
    __shared__ unsigned short hl[HEAVY_K];
    const int lane = threadIdx.x; // 0..63
    for (int c = lane; c < S; c += 64) acc[c] = 0.f;
    {
        float s0 = 0, s1 = 0, s2 = 0, s3 = 0;
        for (int t0 = 0; t0 < START_T; ++t0) {
            const float* Pr = P + (size_t)t0 * S;
            s0 += Pr[lane]; s1 += Pr[lane + 64]; s2 += Pr[lane + 128]; s3 += Pr[lane + 192];
        }
        acc[lane] = s0; acc[lane + 64] = s1; acc[lane + 128] = s2; acc[lane + 192] = s3;
    }
    hl[lane] = (unsigned short)lane;
    hl[lane + 64] = (unsigned short)(lane + 64);
    __syncthreads();
    // t = 256: heavy = {0..127}, mask = [0,256]
    {
        const float* Pr = P + (size_t)START_T * S;
        acc[lane] += Pr[lane]; acc[lane + 64] += Pr[lane + 64];
        acc[lane + 128] += Pr[lane + 128]; acc[lane + 192] += Pr[lane + 192];
        if (lane == 0) acc[256] += Pr[256];
        heavy[START_T * HEAVY_K + lane] = (unsigned short)lane;
        heavy[START_T * HEAVY_K + 64 + lane] = (unsigned short)(lane + 64);
    }
    __syncthreads();
    for (int t = START_T + 1; t < S; ++t) {
        const float* Pr = P + (size_t)t * S;
        // prefetch row t+8 (touch every 64B line) to hide HBM latency
        if (t + 8 < S) {
            const float* Pf = P + (size_t)(t + 8) * S;
            float pre0 = Pf[lane * 16];
            float pre1 = Pf[lane * 16 + 1024];
            asm volatile("" :: "v"(pre0), "v"(pre1));
        }
        const int newc = t - 129;
        int c0 = hl[lane], c1 = hl[lane + 64];
        float v0 = acc[c0], v1 = acc[c1];
        float pv0 = Pr[c0], pv1 = Pr[c1];
        float pnew = Pr[newc];
        const int r0 = t - RECENT_W + lane;
        float pr0 = Pr[r0], pr1 = Pr[r0 + 64];
        float prt = Pr[t];
        float nv = acc[newc];
        // min over 129 candidates (128 heavy + new); tie -> larger col evicted
        float mv; int mc, ms;
        if (v1 < v0 || (v1 == v0 && c1 > c0)) { mv = v1; mc = c1; ms = lane + 64; }
        else                                  { mv = v0; mc = c0; ms = lane; }
#pragma unroll
        for (int off = 32; off > 0; off >>= 1) {
            float ov = __shfl_down(mv, off);
            int   oc = __shfl_down(mc, off);
            int   os = __shfl_down(ms, off);
            if (ov < mv || (ov == mv && oc > mc)) { mv = ov; mc = oc; ms = os; }
        }
        mv = __shfl(mv, 0); mc = __shfl(mc, 0); ms = __shfl(ms, 0);
        bool evict_heavy = (mv < nv); // ties: new col (largest index) evicted
        if (evict_heavy) {
            if (ms == lane)           { acc[c0] = 0.f; c0 = newc; pv0 = pnew; hl[lane] = (unsigned short)newc; }
            else if (ms == lane + 64) { acc[c1] = 0.f; c1 = newc; pv1 = pnew; hl[lane + 64] = (unsigned short)newc; }
        } else if (lane == 0) {
            acc[newc] = 0.f;
        }
        // accumulate row t over mask (heavy ∪ recent[t-128..t])
        acc[c0] += pv0;
        acc[c1] += pv1;
        acc[r0] += pr0;
        acc[r0 + 64] += pr1;
        if (lane == 0) acc[t] += prt;
        heavy[(size_t)t * HEAVY_K + lane] = (unsigned short)c0;
        heavy[(size_t)t * HEAVY_K + 64 + lane] = (unsigned short)c1;
        __syncthreads();
    }
}

// ---------------------------------------------------------------------------
// Sparse masked attention: row t attends to {128 heavy} ∪ [t-128, t]
// (rows t<256: dense causal cols 0..t). One block per row, 256 threads.
// ---------------------------------------------------------------------------
__global__ __launch_bounds__(256) void attn_kernel(const float* __restrict__ q,
                                                   const float* __restrict__ k,
                                                   const float* __restrict__ v,
                                                   const unsigned short* __restrict__ heavy,
                                                   float* __restrict__ attn)
{
    const int t = blockIdx.x;
    const int tid = threadIdx.x;
    __shared__ float qs[HDIM];
    __shared__ float sc[NH][258];
    __shared__ unsigned short cols[260];
    __shared__ float zpart[NH][8];
    __shared__ float zf[NH];
    const int cnt = (t < START_T) ? (t + 1) : 257;
    for (int i = tid; i < HDIM; i += 256) qs[i] = q[(size_t)t * HDIM + i];
    if (t < START_T) {
        for (int j = tid; j < cnt; j += 256) cols[j] = (unsigned short)j;
    } else {
        if (tid < 128) cols[tid] = heavy[(size_t)t * HEAVY_K + tid];
        else           cols[tid] = (unsigned short)(t - 256 + tid); // j=128..255 -> t-128..t-1
        if (tid == 0)  cols[256] = (unsigned short)t;
    }
    __syncthreads();
    // scores: lanes within a wave share column j (h varies per lane)
    {
        const int h = tid & 31;
        const float* qh = qs + h * HD;
        for (int j = tid >> 5; j < cnt; j += 8) {
            const float* kc = k + (size_t)cols[j] * HD;
            float s = 0.f;
#pragma unroll
            for (int dq = 0; dq < 16; ++dq) {
                float4 k4 = ((const float4*)kc)[dq];
                float4 q4 = ((const float4*)qh)[dq];
                s += q4.x * k4.x + q4.y * k4.y + q4.z * k4.z + q4.w * k4.w;
            }
            sc[h][j] = s * 0.125f;
        }
    }
    __syncthreads();
    // exp + partial Z
    {
        const int h2 = tid >> 3, sub = tid & 7;
        float z = 0.f;
        for (int j = sub; j < cnt; j += 8) {
            float e = __expf(sc[h2][j]);
            sc[h2][j] = e;
            z += e;
        }
        zpart[h2][sub] = z;
    }
    __syncthreads();
    if (tid < NH) {
        float z = 0.f;
#pragma unroll
        for (int s2 = 0; s2 < 8; ++s2) z += zpart[tid][s2];
        zf[tid] = 1.0f / z;
    }
    __syncthreads();
    // PV
    {
        const int h2 = tid >> 3;
        const int dbase = (tid & 7) * 8;
        float o[8] = {0, 0, 0, 0, 0, 0, 0, 0};
        for (int j = 0; j < cnt; ++j) {
            float p = sc[h2][j];
            const float* vc = v + (size_t)cols[j] * HD + dbase;
            float4 va = *(const float4*)vc;
            float4 vb = *(const float4*)(vc + 4);
            o[0] += p * va.x; o[1] += p * va.y; o[2] += p * va.z; o[3] += p * va.w;
            o[4] += p * vb.x; o[5] += p * vb.y; o[6] += p * vb.z; o[7] += p * vb.w;
        }
        float zi = zf[h2];
        float* op = attn + (size_t)t * HDIM + h2 * HD + dbase;
        float4 ra = make_float4(o[0] * zi, o[1] * zi, o[2] * zi, o[3] * zi);
        float4 rb = make_float4(o[4] * zi, o[5] * zi, o[6] * zi, o[7] * zi);
        *(float4*)op = ra;
        *(float4*)(op + 4) = rb;
    }
}

// ---------------------------------------------------------------------------
extern "C" void kernel_launch(void* const* d_in, const int* in_sizes, int n_in,
                              void* d_out, int out_size, void* d_ws, size_t ws_size,
                              hipStream_t stream)
{
    (void)in_sizes; (void)n_in; (void)out_size; (void)ws_size;
    const float* hs      = (const float*)d_in[0];
    const float* w_qkv   = (const float*)d_in[1];
    const float* w_dense = (const float*)d_in[2];
    float* out = (float*)d_out;
    char* ws = (char*)d_ws;

    // workspace layout (bytes):
    //   [0, 17825792)              fused (2048x2176) -> then P (2048x2048) -> then attn (2048x2048)
    //   [17825792, 34603008)       q roped [2048][2048]
    //   [34603008, 35127296)       k roped [2048][64]
    //   [35127296, 35651584)       v       [2048][64]
    //   [35651584, 36175872)       heavy   ushort [2048][128]
    float* fused = (float*)(ws);
    float* P     = (float*)(ws);
    float* attn  = (float*)(ws);
    float* q     = (float*)(ws + 17825792);
    float* k     = (float*)(ws + 34603008);
    float* v     = (float*)(ws + 35127296);
    unsigned short* heavy = (unsigned short*)(ws + 35651584);

    dim3 g1(FUSED_N / 64, S / 128);
    gemm_nt_kernel<<<g1, 256, 0, stream>>>(hs, w_qkv, fused, HDIM, FUSED_N);

    int total = S * NJ * HD;
    rope_split_kernel<<<(total + 255) / 256, 256, 0, stream>>>(fused, q, k, v);

    p_kernel<<<S, 256, 0, stream>>>(q, k, P);

    scan_kernel<<<1, 64, 0, stream>>>(P, heavy);

    attn_kernel<<<S, 256, 0, stream>>>(q, k, v, heavy, attn);

    dim3 g2(HDIM / 64, S / 128);
    gemm_nt_kernel<<<g2, 256, 0, stream>>>(attn, w_dense, out, HDIM, HDIM);
}

// Round 2
// 3278.264 us; speedup vs baseline: 3.4189x; 3.4189x over previous
//
#include <hip/hip_runtime.h>
#include <hip/hip_bf16.h>
#include <cstdint>

#define S 2048
#define NH 32
#define HD 64
#define NJ 34              // 32 q heads + k + v
#define FUSED_N (NJ * HD)  // 2176
#define HDIM (NH * HD)     // 2048
#define HEAVY_K 128
#define RECENT_W 128
#define START_T 256

typedef __attribute__((ext_vector_type(8))) short short8;
typedef __attribute__((ext_vector_type(4))) float floatx4;

static __device__ __forceinline__ unsigned short f2bf(float f) {
    unsigned u = __float_as_uint(f);
    unsigned r = (u + 0x7FFF + ((u >> 16) & 1)) >> 16; // round-nearest-even
    return (unsigned short)r;
}
static __device__ __forceinline__ float bf2f(unsigned short b) {
    return __uint_as_float(((unsigned)b) << 16);
}

// ---------------------------------------------------------------------------
// GEMM: C[M x N] = A[M x K] * B[N x K]^T   (fp32)
// tile 128(M) x 64(N), K-step 16, 256 threads, 8x4 micro-tile
// ---------------------------------------------------------------------------
__global__ __launch_bounds__(256) void gemm_nt_kernel(const float* __restrict__ A,
                                                      const float* __restrict__ B,
                                                      float* __restrict__ C,
                                                      int K, int N)
{
    __shared__ float As[16][132];
    __shared__ float Bs[16][68];
    const int bm = blockIdx.y * 128;
    const int bn = blockIdx.x * 64;
    const int tid = threadIdx.x;
    const int tm = (tid >> 4) * 8;
    const int tn = (tid & 15) * 4;
    const int lr = tid >> 2;
    const int lk = (tid & 3) * 4;
    float acc[8][4] = {};
    const float* Ap0 = A + (size_t)(bm + lr) * K + lk;
    const float* Ap1 = Ap0 + (size_t)64 * K;
    const float* Bp  = B + (size_t)(bn + lr) * K + lk;
    for (int k0 = 0; k0 < K; k0 += 16) {
        float4 a0 = *(const float4*)(Ap0 + k0);
        float4 a1 = *(const float4*)(Ap1 + k0);
        float4 b0 = *(const float4*)(Bp + k0);
        As[lk + 0][lr] = a0.x; As[lk + 1][lr] = a0.y; As[lk + 2][lr] = a0.z; As[lk + 3][lr] = a0.w;
        As[lk + 0][lr + 64] = a1.x; As[lk + 1][lr + 64] = a1.y; As[lk + 2][lr + 64] = a1.z; As[lk + 3][lr + 64] = a1.w;
        Bs[lk + 0][lr] = b0.x; Bs[lk + 1][lr] = b0.y; Bs[lk + 2][lr] = b0.z; Bs[lk + 3][lr] = b0.w;
        __syncthreads();
#pragma unroll
        for (int kk = 0; kk < 16; ++kk) {
            float4 av0 = *(const float4*)&As[kk][tm];
            float4 av1 = *(const float4*)&As[kk][tm + 4];
            float4 bv  = *(const float4*)&Bs[kk][tn];
            float a8[8] = {av0.x, av0.y, av0.z, av0.w, av1.x, av1.y, av1.z, av1.w};
            float b4[4] = {bv.x, bv.y, bv.z, bv.w};
#pragma unroll
            for (int i = 0; i < 8; ++i)
#pragma unroll
                for (int j = 0; j < 4; ++j)
                    acc[i][j] += a8[i] * b4[j];
        }
        __syncthreads();
    }
#pragma unroll
    for (int i = 0; i < 8; ++i) {
        float4 r = make_float4(acc[i][0], acc[i][1], acc[i][2], acc[i][3]);
        *(float4*)(C + (size_t)(bm + tm + i) * N + (bn + tn)) = r;
    }
}

// ---------------------------------------------------------------------------
// RoPE + split fused -> qb [S][2048] bf16, kb [S][64] bf16, v [S][64] f32
// ---------------------------------------------------------------------------
__global__ __launch_bounds__(256) void rope_split_kernel(const float* __restrict__ fused,
                                                         unsigned short* __restrict__ qb,
                                                         unsigned short* __restrict__ kb,
                                                         float* __restrict__ v)
{
    int idx = blockIdx.x * 256 + threadIdx.x;
    const int total = S * NJ * HD;
    if (idx >= total) return;
    int t = idx / FUSED_N;
    int rem = idx - t * FUSED_N;
    int j = rem >> 6;
    int d = rem & 63;
    float x = fused[idx];
    if (j == 33) { v[t * HD + d] = x; return; }
    int i = d & 31;
    double inv = exp2(-(double)i * (13.287712379549449 / 32.0)); // 10000^(-i/32)
    double ang = (double)t * inv;
    float c  = (float)cos(ang);
    float sn = (float)sin(ang);
    float xo = fused[idx - d + ((d < 32) ? (d + 32) : (d - 32))];
    float rot = (d < 32) ? -xo : xo;
    unsigned short outv = f2bf(x * c + rot * sn);
    if (j == 32) kb[t * HD + d] = outv;
    else         qb[(size_t)t * HDIM + j * HD + d] = outv;
}

// ---------------------------------------------------------------------------
// z_kernel: Zinv[t][h] = 1 / sum_c exp(q_h[t]·k[c]/8)
// block = (t-tile of 32) x head; 4 waves, each wave covers 512 columns
// ---------------------------------------------------------------------------
__global__ __launch_bounds__(256) void z_kernel(const unsigned short* __restrict__ qb,
                                                const unsigned short* __restrict__ kb,
                                                float* __restrict__ zinv)
{
    const int t0 = blockIdx.x * 32;
    const int h  = blockIdx.y;
    const int w    = threadIdx.x >> 6;
    const int lane = threadIdx.x & 63;
    const int rsub = lane & 15;
    const int d0   = (lane >> 4) * 8;
    __shared__ float zl[4][32];

    short8 a[2][2];
#pragma unroll
    for (int mt = 0; mt < 2; ++mt) {
        const short8* ap = (const short8*)(qb + (size_t)(t0 + mt * 16 + rsub) * HDIM + h * HD + d0);
        a[mt][0] = ap[0];
        a[mt][1] = ap[4]; // +32 elements
    }
    float z[2][4] = {};
    for (int nt = 0; nt < 32; ++nt) {
        const int c = w * 512 + nt * 16 + rsub;
        const short8* bp = (const short8*)(kb + (size_t)c * HD + d0);
        short8 b0 = bp[0];
        short8 b1 = bp[4];
#pragma unroll
        for (int mt = 0; mt < 2; ++mt) {
            floatx4 acc = {0.f, 0.f, 0.f, 0.f};
            acc = __builtin_amdgcn_mfma_f32_16x16x32_bf16(a[mt][0], b0, acc, 0, 0, 0);
            acc = __builtin_amdgcn_mfma_f32_16x16x32_bf16(a[mt][1], b1, acc, 0, 0, 0);
#pragma unroll
            for (int r = 0; r < 4; ++r) z[mt][r] += __expf(acc[r] * 0.125f);
        }
    }
#pragma unroll
    for (int mt = 0; mt < 2; ++mt)
#pragma unroll
        for (int r = 0; r < 4; ++r) {
            float zz = z[mt][r];
#pragma unroll
            for (int off = 1; off < 16; off <<= 1) zz += __shfl_xor(zz, off);
            z[mt][r] = zz;
        }
    if (rsub == 0) {
#pragma unroll
        for (int mt = 0; mt < 2; ++mt)
#pragma unroll
            for (int r = 0; r < 4; ++r)
                zl[w][mt * 16 + (lane >> 4) * 4 + r] = z[mt][r];
    }
    __syncthreads();
    if (threadIdx.x < 32) {
        float s = zl[0][threadIdx.x] + zl[1][threadIdx.x] + zl[2][threadIdx.x] + zl[3][threadIdx.x];
        zinv[(size_t)(t0 + threadIdx.x) * NH + h] = 1.0f / s;
    }
}

// ---------------------------------------------------------------------------
// pnorm_kernel: P[t][c] = sum_h exp(q_h[t]·k[c]/8) * zinv[t][h]
// block = (t-tile 32) x (c-tile 256); 4 waves, 64 cols/wave; loop heads
// ---------------------------------------------------------------------------
__global__ __launch_bounds__(256) void pnorm_kernel(const unsigned short* __restrict__ qb,
                                                    const unsigned short* __restrict__ kb,
                                                    const float* __restrict__ zinv,
                                                    float* __restrict__ P)
{
    const int t0 = blockIdx.y * 32;
    const int cb = blockIdx.x * 256;
    const int w    = threadIdx.x >> 6;
    const int lane = threadIdx.x & 63;
    const int rsub = lane & 15;
    const int d0   = (lane >> 4) * 8;
    __shared__ float zi[32][33];
    for (int i = threadIdx.x; i < 32 * 32; i += 256) {
        int row = i >> 5, hh = i & 31;
        zi[row][hh] = zinv[(size_t)(t0 + row) * NH + hh];
    }
    __syncthreads();

    float pacc[2][4][4] = {};
    for (int h = 0; h < NH; ++h) {
        short8 a[2][2];
#pragma unroll
        for (int mt = 0; mt < 2; ++mt) {
            const short8* ap = (const short8*)(qb + (size_t)(t0 + mt * 16 + rsub) * HDIM + h * HD + d0);
            a[mt][0] = ap[0];
            a[mt][1] = ap[4];
        }
        float zv[2][4];
#pragma unroll
        for (int mt = 0; mt < 2; ++mt)
#pragma unroll
            for (int r = 0; r < 4; ++r)
                zv[mt][r] = zi[mt * 16 + (lane >> 4) * 4 + r][h];
#pragma unroll
        for (int nt = 0; nt < 4; ++nt) {
            const int c = cb + w * 64 + nt * 16 + rsub;
            const short8* bp = (const short8*)(kb + (size_t)c * HD + d0);
            short8 b0 = bp[0];
            short8 b1 = bp[4];
#pragma unroll
            for (int mt = 0; mt < 2; ++mt) {
                floatx4 acc = {0.f, 0.f, 0.f, 0.f};
                acc = __builtin_amdgcn_mfma_f32_16x16x32_bf16(a[mt][0], b0, acc, 0, 0, 0);
                acc = __builtin_amdgcn_mfma_f32_16x16x32_bf16(a[mt][1], b1, acc, 0, 0, 0);
#pragma unroll
                for (int r = 0; r < 4; ++r)
                    pacc[mt][nt][r] += __expf(acc[r] * 0.125f) * zv[mt][r];
            }
        }
    }
#pragma unroll
    for (int mt = 0; mt < 2; ++mt)
#pragma unroll
        for (int nt = 0; nt < 4; ++nt)
#pragma unroll
            for (int r = 0; r < 4; ++r) {
                int row = t0 + mt * 16 + (lane >> 4) * 4 + r;
                int col = cb + w * 64 + nt * 16 + rsub;
                P[(size_t)row * S + col] = pacc[mt][nt][r];
            }
}

// ---------------------------------------------------------------------------
// Sequential heavy-hitter scan. Single block of 64 threads (1 wave).
// Candidates at step t = previous 128 heavy cols + col (t-129): evict min
// (ties -> evict larger column, matching lax.top_k ascending-index tie-break).
// ---------------------------------------------------------------------------
__global__ void scan_kernel(const float* __restrict__ P, unsigned short* __restrict__ heavy)
{
    __shared__ float acc[S];
    __shared__ unsigned short hl[HEAVY_K];
    const int lane = threadIdx.x; // 0..63
    for (int c = lane; c < S; c += 64) acc[c] = 0.f;
    {
        float s0 = 0, s1 = 0, s2 = 0, s3 = 0;
        for (int t0 = 0; t0 < START_T; ++t0) {
            const float* Pr = P + (size_t)t0 * S;
            s0 += Pr[lane]; s1 += Pr[lane + 64]; s2 += Pr[lane + 128]; s3 += Pr[lane + 192];
        }
        acc[lane] = s0; acc[lane + 64] = s1; acc[lane + 128] = s2; acc[lane + 192] = s3;
    }
    hl[lane] = (unsigned short)lane;
    hl[lane + 64] = (unsigned short)(lane + 64);
    __syncthreads();
    {
        const float* Pr = P + (size_t)START_T * S;
        acc[lane] += Pr[lane]; acc[lane + 64] += Pr[lane + 64];
        acc[lane + 128] += Pr[lane + 128]; acc[lane + 192] += Pr[lane + 192];
        if (lane == 0) acc[256] += Pr[256];
        heavy[START_T * HEAVY_K + lane] = (unsigned short)lane;
        heavy[START_T * HEAVY_K + 64 + lane] = (unsigned short)(lane + 64);
    }
    __syncthreads();
    for (int t = START_T + 1; t < S; ++t) {
        const float* Pr = P + (size_t)t * S;
        if (t + 8 < S) {
            const float* Pf = P + (size_t)(t + 8) * S;
            float pre0 = Pf[lane * 16];
            float pre1 = Pf[lane * 16 + 1024];
            asm volatile("" :: "v"(pre0), "v"(pre1));
        }
        const int newc = t - 129;
        int c0 = hl[lane], c1 = hl[lane + 64];
        float v0 = acc[c0], v1 = acc[c1];
        float pv0 = Pr[c0], pv1 = Pr[c1];
        float pnew = Pr[newc];
        const int r0 = t - RECENT_W + lane;
        float pr0 = Pr[r0], pr1 = Pr[r0 + 64];
        float prt = Pr[t];
        float nv = acc[newc];
        float mv; int mc, ms;
        if (v1 < v0 || (v1 == v0 && c1 > c0)) { mv = v1; mc = c1; ms = lane + 64; }
        else                                  { mv = v0; mc = c0; ms = lane; }
#pragma unroll
        for (int off = 32; off > 0; off >>= 1) {
            float ov = __shfl_down(mv, off);
            int   oc = __shfl_down(mc, off);
            int   os = __shfl_down(ms, off);
            if (ov < mv || (ov == mv && oc > mc)) { mv = ov; mc = oc; ms = os; }
        }
        mv = __shfl(mv, 0); mc = __shfl(mc, 0); ms = __shfl(ms, 0);
        bool evict_heavy = (mv < nv);
        if (evict_heavy) {
            if (ms == lane)           { acc[c0] = 0.f; c0 = newc; pv0 = pnew; hl[lane] = (unsigned short)newc; }
            else if (ms == lane + 64) { acc[c1] = 0.f; c1 = newc; pv1 = pnew; hl[lane + 64] = (unsigned short)newc; }
        } else if (lane == 0) {
            acc[newc] = 0.f;
        }
        acc[c0] += pv0;
        acc[c1] += pv1;
        acc[r0] += pr0;
        acc[r0 + 64] += pr1;
        if (lane == 0) acc[t] += prt;
        heavy[(size_t)t * HEAVY_K + lane] = (unsigned short)c0;
        heavy[(size_t)t * HEAVY_K + 64 + lane] = (unsigned short)c1;
        __syncthreads();
    }
}

// ---------------------------------------------------------------------------
// Sparse masked attention: row t attends to {128 heavy} ∪ [t-128, t]
// (rows t<256: dense causal). q/k read as bf16, compute fp32; v fp32.
// ---------------------------------------------------------------------------
__global__ __launch_bounds__(256) void attn_kernel(const unsigned short* __restrict__ qb,
                                                   const unsigned short* __restrict__ kb,
                                                   const float* __restrict__ v,
                                                   const unsigned short* __restrict__ heavy,
                                                   float* __restrict__ attn)
{
    const int t = blockIdx.x;
    const int tid = threadIdx.x;
    __shared__ float qs[HDIM];
    __shared__ float sc[NH][258];
    __shared__ unsigned short cols[260];
    __shared__ float zpart[NH][8];
    __shared__ float zf[NH];
    const int cnt = (t < START_T) ? (t + 1) : 257;
    {
        const short8* qr = (const short8*)(qb + (size_t)t * HDIM);
        short8 qv = qr[tid];
#pragma unroll
        for (int j = 0; j < 8; ++j) qs[tid * 8 + j] = bf2f((unsigned short)qv[j]);
    }
    if (t < START_T) {
        for (int j = tid; j < cnt; j += 256) cols[j] = (unsigned short)j;
    } else {
        if (tid < 128) cols[tid] = heavy[(size_t)t * HEAVY_K + tid];
        else           cols[tid] = (unsigned short)(t - 256 + tid);
        if (tid == 0)  cols[256] = (unsigned short)t;
    }
    __syncthreads();
    {
        const int h = tid & 31;
        const float* qh = qs + h * HD;
        for (int j = tid >> 5; j < cnt; j += 8) {
            const short8* kc8 = (const short8*)(kb + (size_t)cols[j] * HD);
            float s = 0.f;
#pragma unroll
            for (int dq = 0; dq < 8; ++dq) {
                short8 kv = kc8[dq];
#pragma unroll
                for (int e = 0; e < 8; ++e)
                    s += qh[dq * 8 + e] * bf2f((unsigned short)kv[e]);
            }
            sc[h][j] = s * 0.125f;
        }
    }
    __syncthreads();
    {
        const int h2 = tid >> 3, sub = tid & 7;
        float z = 0.f;
        for (int j = sub; j < cnt; j += 8) {
            float e = __expf(sc[h2][j]);
            sc[h2][j] = e;
            z += e;
        }
        zpart[h2][sub] = z;
    }
    __syncthreads();
    if (tid < NH) {
        float z = 0.f;
#pragma unroll
        for (int s2 = 0; s2 < 8; ++s2) z += zpart[tid][s2];
        zf[tid] = 1.0f / z;
    }
    __syncthreads();
    {
        const int h2 = tid >> 3;
        const int dbase = (tid & 7) * 8;
        float o[8] = {0, 0, 0, 0, 0, 0, 0, 0};
        for (int j = 0; j < cnt; ++j) {
            float p = sc[h2][j];
            const float* vc = v + (size_t)cols[j] * HD + dbase;
            float4 va = *(const float4*)vc;
            float4 vb = *(const float4*)(vc + 4);
            o[0] += p * va.x; o[1] += p * va.y; o[2] += p * va.z; o[3] += p * va.w;
            o[4] += p * vb.x; o[5] += p * vb.y; o[6] += p * vb.z; o[7] += p * vb.w;
        }
        float zi = zf[h2];
        float* op = attn + (size_t)t * HDIM + h2 * HD + dbase;
        float4 ra = make_float4(o[0] * zi, o[1] * zi, o[2] * zi, o[3] * zi);
        float4 rb = make_float4(o[4] * zi, o[5] * zi, o[6] * zi, o[7] * zi);
        *(float4*)op = ra;
        *(float4*)(op + 4) = rb;
    }
}

// ---------------------------------------------------------------------------
extern "C" void kernel_launch(void* const* d_in, const int* in_sizes, int n_in,
                              void* d_out, int out_size, void* d_ws, size_t ws_size,
                              hipStream_t stream)
{
    (void)in_sizes; (void)n_in; (void)out_size; (void)ws_size;
    const float* hs      = (const float*)d_in[0];
    const float* w_qkv   = (const float*)d_in[1];
    const float* w_dense = (const float*)d_in[2];
    float* out = (float*)d_out;
    char* ws = (char*)d_ws;

    // workspace layout (bytes):
    //   [0, 17825792)            fused (2048x2176 f32) -> P (2048x2048 f32) -> attn (2048x2048 f32)
    //   [17825792, 26214400)     qb  bf16 [2048][2048]
    //   [26214400, 26476544)     kb  bf16 [2048][64]
    //   [26476544, 27000832)     v   f32  [2048][64]
    //   [27000832, 27262976)     zinv f32 [2048][32]
    //   [27262976, 27787264)     heavy ushort [2048][128]
    float* fused = (float*)(ws);
    float* P     = (float*)(ws);
    float* attn  = (float*)(ws);
    unsigned short* qb = (unsigned short*)(ws + 17825792);
    unsigned short* kb = (unsigned short*)(ws + 26214400);
    float* v           = (float*)(ws + 26476544);
    float* zinv        = (float*)(ws + 27000832);
    unsigned short* heavy = (unsigned short*)(ws + 27262976);

    dim3 g1(FUSED_N / 64, S / 128);
    gemm_nt_kernel<<<g1, 256, 0, stream>>>(hs, w_qkv, fused, HDIM, FUSED_N);

    int total = S * NJ * HD;
    rope_split_kernel<<<(total + 255) / 256, 256, 0, stream>>>(fused, qb, kb, v);

    dim3 gz(S / 32, NH);
    z_kernel<<<gz, 256, 0, stream>>>(qb, kb, zinv);

    dim3 gp(S / 256, S / 32);
    pnorm_kernel<<<gp, 256, 0, stream>>>(qb, kb, zinv, P);

    scan_kernel<<<1, 64, 0, stream>>>(P, heavy);

    attn_kernel<<<S, 256, 0, stream>>>(qb, kb, v, heavy, attn);

    dim3 g2(HDIM / 64, S / 128);
    gemm_nt_kernel<<<g2, 256, 0, stream>>>(attn, w_dense, out, HDIM, HDIM);
}